// Round 1
// baseline (200.833 us; speedup 1.0000x reference)
//
#include <hip/hip_runtime.h>
#include <hip/hip_bf16.h>

#define B_    1024
#define N_    128
#define FEAT_ 512
#define HID_  256

typedef __bf16 bf16x8 __attribute__((ext_vector_type(8)));
typedef float  f32x4  __attribute__((ext_vector_type(4)));

__device__ __forceinline__ unsigned int f2bf(float f) {
    unsigned int u = __float_as_uint(f);
    u += 0x7fffu + ((u >> 16) & 1u);   // round-to-nearest-even
    return u >> 16;
}
__device__ __forceinline__ unsigned int pack2(float a, float b) {
    return f2bf(a) | (f2bf(b) << 16);
}

// ---------------- prep: proj (blocks 0..127) + conv (blocks 128..1151), 512 thr ----------------
// proj: 8 b-rows/block (wave = row), thread owns 4 consecutive h -> float4 W loads
//   (all 8 waves load identical addresses -> L1 broadcast). Explicit 2-stage register
//   prefetch (A/B x 8 float4) hides L2 latency; 2 waves/SIMD give TLP on top.
//   Old version was 1 wave/SIMD scalar loads -> ~33us latency-serial tail (the 43.5us,
//   occ 24%, VALU 12% signature).
// conv: 32-row tile/block (n, jg2). Thread owns 2 granules: 32B fp32 load -> uint4 store
//   at swizzled granule g2 = gc ^ ((j&7)<<2) (note (r0+16i)&7 == r0&7). sv[32][33] + shuffles
//   produce v2[j] = 2*sum_k mu_k M[j,k]; cpart[n*8+jg2] = block partial of mu^T M mu.
__global__ __launch_bounds__(512) void prep_kernel(
    const float* __restrict__ x, const float* __restrict__ W,
    const float* __restrict__ bias, const float* __restrict__ means,
    const float* __restrict__ invcov,
    float* __restrict__ xp, unsigned short* __restrict__ xbf,
    unsigned short* __restrict__ Mbf, float* __restrict__ v2,
    float* __restrict__ cpart, float* __restrict__ out)
{
    const int t = threadIdx.x;
    if (blockIdx.x < 128) {
        // ---------------- proj role ----------------
        __shared__ float xs[8][FEAT_];          // 16 KB
        const int b0 = blockIdx.x * 8;
        {
            const float4* xsrc = (const float4*)(x + (size_t)b0 * FEAT_);  // 1024 float4
            ((float4*)&xs[0][0])[t]       = xsrc[t];
            ((float4*)&xs[0][0])[t + 512] = xsrc[t + 512];
        }
        if (blockIdx.x == 0 && t == 0) out[0] = (float)(N_ - 1) * 1e-12f;  // clip residue init
        __syncthreads();
        const int row = t >> 6;                 // 0..7 (wave = row)
        const int h4  = t & 63;                 // float4 column (h = h4*4 .. h4*4+3)
        const float* __restrict__ xr = &xs[row][0];
        const float4* Wv = (const float4*)W;    // [512][64] float4
        float4 acc = ((const float4*)bias)[h4];
        float4 Abuf[8], Bbuf[8];                // 2-stage prefetch, 64 VGPR
        auto LD = [&](float4 (&buf)[8], int g) {
            #pragma unroll
            for (int u = 0; u < 8; ++u) buf[u] = Wv[(size_t)(g * 8 + u) * 64 + h4];
        };
        auto FMA8 = [&](const float4 (&buf)[8], int g) {
            const float4 xa = *(const float4*)(xr + g * 8);
            const float4 xb = *(const float4*)(xr + g * 8 + 4);
            const float xv[8] = {xa.x, xa.y, xa.z, xa.w, xb.x, xb.y, xb.z, xb.w};
            #pragma unroll
            for (int u = 0; u < 8; ++u) {       // all indices compile-time after unroll
                acc.x += xv[u] * buf[u].x;
                acc.y += xv[u] * buf[u].y;
                acc.z += xv[u] * buf[u].z;
                acc.w += xv[u] * buf[u].w;
            }
        };
        LD(Abuf, 0);
        for (int g = 0; g < 62; g += 2) {       // groups of 8 f; 0..63 total
            LD(Bbuf, g + 1);
            FMA8(Abuf, g);
            LD(Abuf, g + 2);
            FMA8(Bbuf, g + 1);
        }
        LD(Bbuf, 63);
        FMA8(Abuf, 62);
        FMA8(Bbuf, 63);
        const int gr = b0 + row;
        ((float4*)(xp + (size_t)gr * HID_))[h4] = acc;
        *(uint2*)(xbf + (size_t)gr * HID_ + h4 * 4) =
            make_uint2(pack2(acc.x, acc.y), pack2(acc.z, acc.w));
    } else {
        // ---------------- conv role ----------------
        __shared__ float sv[32][33];
        __shared__ float sw[4];
        const int cb  = blockIdx.x - 128;  // 0..1023
        const int n   = cb >> 3;           // 0..127
        const int jg2 = cb & 7;            // 32-row group
        const float* Mn = invcov + (size_t)n * (HID_ * HID_) + (size_t)jg2 * 32 * HID_;
        const float* mu = means + (size_t)n * HID_;
        unsigned short* Mb = Mbf + (size_t)n * (HID_ * HID_) + (size_t)jg2 * 32 * HID_;
        const int gc = t & 31;             // granule column (k = gc*8 .. gc*8+7)
        const int r0 = t >> 5;             // 0..15 -> rows r0 and r0+16
        const float4 mk0 = *(const float4*)(mu + gc * 8);
        const float4 mk1 = *(const float4*)(mu + gc * 8 + 4);
        #pragma unroll
        for (int i = 0; i < 2; ++i) {
            const int row = r0 + i * 16;   // local 0..31; global j = jg2*32+row, j&7 == row&7
            const float* src = Mn + (size_t)row * HID_ + gc * 8;
            const float4 a = *(const float4*)src;
            const float4 b = *(const float4*)(src + 4);
            const int g2 = gc ^ ((row & 7) << 2);
            *(uint4*)(Mb + (size_t)row * HID_ + g2 * 8) =
                make_uint4(pack2(a.x, a.y), pack2(a.z, a.w), pack2(b.x, b.y), pack2(b.z, b.w));
            sv[row][gc] = a.x * mk0.x + a.y * mk0.y + a.z * mk0.z + a.w * mk0.w
                        + b.x * mk1.x + b.y * mk1.y + b.z * mk1.z + b.w * mk1.w;
        }
        __syncthreads();
        if (t < 256) {
            const int row = t >> 3;        // 0..31 (8 rows per wave)
            const int i0  = (t & 7) * 4;
            float v = sv[row][i0] + sv[row][i0 + 1] + sv[row][i0 + 2] + sv[row][i0 + 3];
            v += __shfl_xor(v, 1);         // reduce across the 8 gc-groups
            v += __shfl_xor(v, 2);
            v += __shfl_xor(v, 4);
            const int j = jg2 * 32 + row;
            if ((t & 7) == 0) v2[(size_t)n * HID_ + j] = 2.f * v;
            float cc = ((t & 7) == 0) ? v * mu[j] : 0.f;
            cc += __shfl_xor(cc, 8);       // sum the 8 rows of this wave
            cc += __shfl_xor(cc, 16);
            cc += __shfl_xor(cc, 32);
            if ((t & 63) == 0) sw[t >> 6] = cc;
        }
        __syncthreads();
        if (t == 0) cpart[cb] = sw[0] + sw[1] + sw[2] + sw[3];
    }
}

// ---------------- dist: p[jh][b][n] = sum_{j in half} (T[b,j] - v2[n,j]) * xp[b,j] ----------------
// T = x . M_n (bf16 MFMA, fp32 acc). grid (4 bg, 2 jh, 128 n) = 1024 blocks,
// 512 threads, 64 KB LDS -> 2 blocks/CU. M-half staged by pure global_load_lds DMA
// (pre-converted, pre-swizzled bf16) — zero staging VALU. Wave owns 32 b-rows; afrag
// (x rows, bf16, full K) resident in 64 regs; per ct: 8 ds_read_b128 (2-way only) + 16 MFMA.
__global__ __launch_bounds__(512, 4) void dist_kernel(
    const float* __restrict__ xp, const unsigned short* __restrict__ xbf,
    const unsigned short* __restrict__ Mbf, const float* __restrict__ v2,
    float* __restrict__ p)
{
    extern __shared__ unsigned short Ms[];   // 128 rows x 256 el (swizzled) = 65536 B

    const int tid  = threadIdx.x;
    const int bh   = blockIdx.x;       // 0..3
    const int jh   = blockIdx.y;       // 0..1
    const int n    = blockIdx.z;       // 0..127
    const int wave = tid >> 6;
    const int lane = tid & 63;
    const int q    = lane >> 4;        // quad 0..3
    const int l    = lane & 15;

    // ---- DMA stage 64 KB M-half: 64 chunks of 1 KB (wave, iter) ----
    const unsigned short* src = Mbf + (size_t)n * (HID_ * HID_) + (size_t)jh * 32768;
    #pragma unroll
    for (int i = 0; i < 8; ++i) {
        const int c = i * 8 + wave;    // chunk id, wave-uniform
        __builtin_amdgcn_global_load_lds(
            (const __attribute__((address_space(1))) unsigned int*)(src + (size_t)c * 512 + lane * 8),
            (__attribute__((address_space(3))) unsigned int*)&Ms[c * 512],
            16, 0, 0);
    }

    // ---- afrag: x rows (bf16, pre-converted), full K, 2 row-blocks of 16 ----
    // A layout: A[m=lane&15][k=quad*8+j]
    bf16x8 afrag[2][8];
    #pragma unroll
    for (int rb = 0; rb < 2; ++rb) {
        const unsigned short* xr = xbf + (size_t)(bh * 256 + wave * 32 + rb * 16 + l) * HID_;
        #pragma unroll
        for (int kk = 0; kk < 8; ++kk)
            afrag[rb][kk] = *(const bf16x8*)(xr + kk * 32 + q * 8);
    }
    // v2 per lane per ct (j = jh*128 + ct*16 + l)
    float v2l[8];
    #pragma unroll
    for (int ct = 0; ct < 8; ++ct)
        v2l[ct] = v2[(size_t)n * HID_ + jh * 128 + ct * 16 + l];

    __syncthreads();   // drains the DMA (vmcnt) + the only barrier

    float part[8];
    #pragma unroll
    for (int i = 0; i < 8; ++i) part[i] = 0.f;

    // epilogue x source: row (bh*256 + wave*32 + q*4 + r + rb*16), col (jh*128 + ct*16 + l)
    const size_t xbase = (size_t)(bh * 256 + wave * 32 + q * 4) * HID_ + jh * 128 + l;

    #pragma unroll
    for (int ct = 0; ct < 8; ++ct) {
        // hoist fp32 x loads for the fused epilogue
        float xl[8];
        #pragma unroll
        for (int rb = 0; rb < 2; ++rb)
            #pragma unroll
            for (int r = 0; r < 4; ++r)
                xl[rb * 4 + r] = xp[xbase + (size_t)(rb * 16 + r) * HID_ + ct * 16];

        f32x4 acc0 = {0.f,0.f,0.f,0.f}, acc1 = {0.f,0.f,0.f,0.f};
        #pragma unroll
        for (int kk = 0; kk < 8; ++kk) {
            // swizzled read: row jr=ct*16+l, granule (kk*4+q)^((l&7)<<2)  -> 2-way banks (free)
            const bf16x8 bfrag = *(const bf16x8*)&Ms[(ct * 16 + l) * HID_ +
                                                     (((kk * 4 + q) ^ ((l & 7) << 2)) << 3)];
            acc0 = __builtin_amdgcn_mfma_f32_16x16x32_bf16(afrag[0][kk], bfrag, acc0, 0, 0, 0);
            acc1 = __builtin_amdgcn_mfma_f32_16x16x32_bf16(afrag[1][kk], bfrag, acc1, 0, 0, 0);
        }
        // fused epilogue: part += (T - v2) * x   (C/D layout: col=lane&15, row=quad*4+reg)
        const float vv = v2l[ct];
        #pragma unroll
        for (int r = 0; r < 4; ++r) {
            part[r]     += (acc0[r] - vv) * xl[r];
            part[4 + r] += (acc1[r] - vv) * xl[4 + r];
        }
    }

    // reduce across the 16 col-lanes of each quad
    #pragma unroll
    for (int i = 0; i < 8; ++i) {
        float v = part[i];
        v += __shfl_xor(v, 1);
        v += __shfl_xor(v, 2);
        v += __shfl_xor(v, 4);
        v += __shfl_xor(v, 8);
        part[i] = v;
    }
    if (l == 0) {
        float* pb = p + (size_t)jh * (B_ * N_);
        #pragma unroll
        for (int i = 0; i < 8; ++i) {
            const int row = bh * 256 + wave * 32 + (i >> 2) * 16 + q * 4 + (i & 3);
            pb[(size_t)row * N_ + n] = part[i];
        }
    }
}

// ---------------- finalize (+fused loss): distmat = sqrt(p0 + p1 + c[n] + 1e-12),
// loss partial = sum of label-selected entries (exactly 2 per 256-thread block),
// atomicAdd'ed /B onto out[0] (pre-initialized with clip residue by prep).
__global__ __launch_bounds__(256) void finalize_kernel(
    const float* __restrict__ p, const float* __restrict__ cpart,
    const int* __restrict__ labels, float* __restrict__ out)
{
    __shared__ float sc[128];
    __shared__ float ls[4];
    const int t = threadIdx.x;
    if (t < 128) {
        float s = 0.f;
        #pragma unroll
        for (int g = 0; g < 8; ++g) s += cpart[t * 8 + g];
        sc[t] = s;
    }
    __syncthreads();
    const int i = blockIdx.x * 256 + t;             // 0..131071
    const int n = i & (N_ - 1);
    const int b = i >> 7;
    const float d = sqrtf(p[i] + p[B_ * N_ + i] + sc[n] + 1e-12f);
    out[1 + i] = d;
    float sel = (labels[b] == n) ? d : 0.f;
    #pragma unroll
    for (int m = 1; m <= 32; m <<= 1) sel += __shfl_xor(sel, m);
    if ((t & 63) == 0) ls[t >> 6] = sel;
    __syncthreads();
    if (t == 0) atomicAdd(out, (ls[0] + ls[1] + ls[2] + ls[3]) * (1.f / (float)B_));
}

extern "C" void kernel_launch(void* const* d_in, const int* in_sizes, int n_in,
                              void* d_out, int out_size, void* d_ws, size_t ws_size,
                              hipStream_t stream) {
    const float* x      = (const float*)d_in[0];
    const int*   labels = (const int*)d_in[1];
    const float* W      = (const float*)d_in[2];
    const float* bias   = (const float*)d_in[3];
    const float* means  = (const float*)d_in[4];
    const float* invcov = (const float*)d_in[5];
    float* out = (float*)d_out;

    // workspace carve-up (~19.5 MB total)
    char* ws = (char*)d_ws;
    unsigned short* Mbf   = (unsigned short*)(ws);               // 16,777,216 B
    float*          xp    = (float*)         (ws + 16777216);    //  1,048,576 B
    unsigned short* xbf   = (unsigned short*)(ws + 17825792);    //    524,288 B
    float*          v2    = (float*)         (ws + 18350080);    //    131,072 B
    float*          cpart = (float*)         (ws + 18481152);    //      4,096 B
    float*          p     = (float*)         (ws + 18489344);    //  1,048,576 B

    constexpr int DIST_LDS = 128 * HID_ * 2;   // 65536 B dynamic LDS
    (void)hipFuncSetAttribute((const void*)dist_kernel,
                              hipFuncAttributeMaxDynamicSharedMemorySize, DIST_LDS);

    prep_kernel<<<dim3(1152), 512, 0, stream>>>(x, W, bias, means, invcov,
                                                xp, xbf, Mbf, v2, cpart, out);
    dist_kernel<<<dim3(4, 2, N_), 512, DIST_LDS, stream>>>(xp, xbf, Mbf, v2, p);
    finalize_kernel<<<dim3((B_ * N_) / 256), 256, 0, stream>>>(p, cpart, labels, out);
}

// Round 2
// 144.018 us; speedup vs baseline: 1.3945x; 1.3945x over previous
//
#include <hip/hip_runtime.h>
#include <hip/hip_bf16.h>

#define B_    1024
#define N_    128
#define FEAT_ 512
#define HID_  256

typedef __bf16 bf16x8 __attribute__((ext_vector_type(8)));
typedef float  f32x4  __attribute__((ext_vector_type(4)));

__device__ __forceinline__ unsigned int f2bf(float f) {
    unsigned int u = __float_as_uint(f);
    u += 0x7fffu + ((u >> 16) & 1u);   // round-to-nearest-even
    return u >> 16;
}
__device__ __forceinline__ unsigned int pack2(float a, float b) {
    return f2bf(a) | (f2bf(b) << 16);
}

// ---------------- prep: proj (blocks 0..511) + conv (blocks 512..1535), 512 thr ----------------
// proj: 2 b-rows/block, 1 scalar output/thread (row = t>>8, h = t&255). W loads coalesced
//   scalar (wave = 64 consecutive h = 256B), explicit 16-deep A/B register prefetch
//   (32 VGPR). 2 blocks/CU -> 4 waves/SIMD TLP on top of the ILP.
//   launch_bounds(512,4) caps VGPR at 128 so the pipeline actually gets registers —
//   round-1 failure: default regalloc targeted 8 waves/EU -> VGPR 36 -> pipeline
//   collapsed to serialized load-use (85us, VALU 5.5%, occ 16%).
// conv: 32-row tile/block (n, jg2). Thread owns 2 granules: 32B fp32 load -> uint4 store
//   at swizzled granule g2 = gc ^ ((j&7)<<2) (note (r0+16i)&7 == r0&7). sv[32][33] + shuffles
//   produce v2[j] = 2*sum_k mu_k M[j,k]; cpart[n*8+jg2] = block partial of mu^T M mu.
__global__ __launch_bounds__(512, 4) void prep_kernel(
    const float* __restrict__ x, const float* __restrict__ W,
    const float* __restrict__ bias, const float* __restrict__ means,
    const float* __restrict__ invcov,
    float* __restrict__ xp, unsigned short* __restrict__ xbf,
    unsigned short* __restrict__ Mbf, float* __restrict__ v2,
    float* __restrict__ cpart, float* __restrict__ out)
{
    const int t = threadIdx.x;
    if (blockIdx.x < 512) {
        // ---------------- proj role ----------------
        __shared__ float xs[2][FEAT_];          // 4 KB
        const int b0 = blockIdx.x * 2;
        if (t < 256)
            ((float4*)&xs[0][0])[t] = ((const float4*)(x + (size_t)b0 * FEAT_))[t];
        if (blockIdx.x == 0 && t == 0) out[0] = (float)(N_ - 1) * 1e-12f;  // clip residue
        __syncthreads();
        const int row = t >> 8;                 // 0..1
        const int h   = t & 255;                // output column
        const float* __restrict__ xr = &xs[row][0];
        float acc = bias[h];
        float Ab[16], Bb[16];                   // A/B prefetch, 16 loads in flight
        auto LD = [&](float (&buf)[16], int g) {
            #pragma unroll
            for (int u = 0; u < 16; ++u) buf[u] = W[(size_t)(g * 16 + u) * HID_ + h];
        };
        auto FM = [&](const float (&buf)[16], int g) {
            #pragma unroll
            for (int u = 0; u < 16; ++u) acc += xr[g * 16 + u] * buf[u];
        };
        LD(Ab, 0);
        for (int g = 0; g < 30; g += 2) {       // 32 groups of 16 f
            LD(Bb, g + 1);
            FM(Ab, g);
            LD(Ab, g + 2);
            FM(Bb, g + 1);
        }
        LD(Bb, 31);
        FM(Ab, 30);
        FM(Bb, 31);
        const int gr = b0 + row;
        xp [(size_t)gr * HID_ + h] = acc;
        xbf[(size_t)gr * HID_ + h] = (unsigned short)f2bf(acc);
    } else {
        // ---------------- conv role ----------------
        __shared__ float sv[32][33];
        __shared__ float sw[4];
        const int cb  = blockIdx.x - 512;  // 0..1023
        const int n   = cb >> 3;           // 0..127
        const int jg2 = cb & 7;            // 32-row group
        const float* Mn = invcov + (size_t)n * (HID_ * HID_) + (size_t)jg2 * 32 * HID_;
        const float* mu = means + (size_t)n * HID_;
        unsigned short* Mb = Mbf + (size_t)n * (HID_ * HID_) + (size_t)jg2 * 32 * HID_;
        const int gc = t & 31;             // granule column (k = gc*8 .. gc*8+7)
        const int r0 = t >> 5;             // 0..15 -> rows r0 and r0+16
        const float4 mk0 = *(const float4*)(mu + gc * 8);
        const float4 mk1 = *(const float4*)(mu + gc * 8 + 4);
        #pragma unroll
        for (int i = 0; i < 2; ++i) {
            const int row = r0 + i * 16;   // local 0..31; global j = jg2*32+row, j&7 == row&7
            const float* src = Mn + (size_t)row * HID_ + gc * 8;
            const float4 a = *(const float4*)src;
            const float4 b = *(const float4*)(src + 4);
            const int g2 = gc ^ ((row & 7) << 2);
            *(uint4*)(Mb + (size_t)row * HID_ + g2 * 8) =
                make_uint4(pack2(a.x, a.y), pack2(a.z, a.w), pack2(b.x, b.y), pack2(b.z, b.w));
            sv[row][gc] = a.x * mk0.x + a.y * mk0.y + a.z * mk0.z + a.w * mk0.w
                        + b.x * mk1.x + b.y * mk1.y + b.z * mk1.z + b.w * mk1.w;
        }
        __syncthreads();
        if (t < 256) {
            const int row = t >> 3;        // 0..31 (8 rows per wave)
            const int i0  = (t & 7) * 4;
            float v = sv[row][i0] + sv[row][i0 + 1] + sv[row][i0 + 2] + sv[row][i0 + 3];
            v += __shfl_xor(v, 1);         // reduce across the 8 gc-groups
            v += __shfl_xor(v, 2);
            v += __shfl_xor(v, 4);
            const int j = jg2 * 32 + row;
            if ((t & 7) == 0) v2[(size_t)n * HID_ + j] = 2.f * v;
            float cc = ((t & 7) == 0) ? v * mu[j] : 0.f;
            cc += __shfl_xor(cc, 8);       // sum the 8 rows of this wave
            cc += __shfl_xor(cc, 16);
            cc += __shfl_xor(cc, 32);
            if ((t & 63) == 0) sw[t >> 6] = cc;
        }
        __syncthreads();
        if (t == 0) cpart[cb] = sw[0] + sw[1] + sw[2] + sw[3];
    }
}

// ---------------- dist: p[jh][b][n] = sum_{j in half} (T[b,j] - v2[n,j]) * xp[b,j] ----------------
// T = x . M_n (bf16 MFMA, fp32 acc). grid (4 bg, 2 jh, 128 n) = 1024 blocks,
// 512 threads, 64 KB LDS -> 2 blocks/CU. M-half staged by pure global_load_lds DMA
// (pre-converted, pre-swizzled bf16) — zero staging VALU. Wave owns 32 b-rows; afrag
// (x rows, bf16, full K) resident in 64 regs; per ct: 8 ds_read_b128 (2-way only) + 16 MFMA.
__global__ __launch_bounds__(512, 4) void dist_kernel(
    const float* __restrict__ xp, const unsigned short* __restrict__ xbf,
    const unsigned short* __restrict__ Mbf, const float* __restrict__ v2,
    float* __restrict__ p)
{
    extern __shared__ unsigned short Ms[];   // 128 rows x 256 el (swizzled) = 65536 B

    const int tid  = threadIdx.x;
    const int bh   = blockIdx.x;       // 0..3
    const int jh   = blockIdx.y;       // 0..1
    const int n    = blockIdx.z;       // 0..127
    const int wave = tid >> 6;
    const int lane = tid & 63;
    const int q    = lane >> 4;        // quad 0..3
    const int l    = lane & 15;

    // ---- DMA stage 64 KB M-half: 64 chunks of 1 KB (wave, iter) ----
    const unsigned short* src = Mbf + (size_t)n * (HID_ * HID_) + (size_t)jh * 32768;
    #pragma unroll
    for (int i = 0; i < 8; ++i) {
        const int c = i * 8 + wave;    // chunk id, wave-uniform
        __builtin_amdgcn_global_load_lds(
            (const __attribute__((address_space(1))) unsigned int*)(src + (size_t)c * 512 + lane * 8),
            (__attribute__((address_space(3))) unsigned int*)&Ms[c * 512],
            16, 0, 0);
    }

    // ---- afrag: x rows (bf16, pre-converted), full K, 2 row-blocks of 16 ----
    // A layout: A[m=lane&15][k=quad*8+j]
    bf16x8 afrag[2][8];
    #pragma unroll
    for (int rb = 0; rb < 2; ++rb) {
        const unsigned short* xr = xbf + (size_t)(bh * 256 + wave * 32 + rb * 16 + l) * HID_;
        #pragma unroll
        for (int kk = 0; kk < 8; ++kk)
            afrag[rb][kk] = *(const bf16x8*)(xr + kk * 32 + q * 8);
    }
    // v2 per lane per ct (j = jh*128 + ct*16 + l)
    float v2l[8];
    #pragma unroll
    for (int ct = 0; ct < 8; ++ct)
        v2l[ct] = v2[(size_t)n * HID_ + jh * 128 + ct * 16 + l];

    __syncthreads();   // drains the DMA (vmcnt) + the only barrier

    float part[8];
    #pragma unroll
    for (int i = 0; i < 8; ++i) part[i] = 0.f;

    // epilogue x source: row (bh*256 + wave*32 + q*4 + r + rb*16), col (jh*128 + ct*16 + l)
    const size_t xbase = (size_t)(bh * 256 + wave * 32 + q * 4) * HID_ + jh * 128 + l;

    #pragma unroll
    for (int ct = 0; ct < 8; ++ct) {
        // hoist fp32 x loads for the fused epilogue
        float xl[8];
        #pragma unroll
        for (int rb = 0; rb < 2; ++rb)
            #pragma unroll
            for (int r = 0; r < 4; ++r)
                xl[rb * 4 + r] = xp[xbase + (size_t)(rb * 16 + r) * HID_ + ct * 16];

        f32x4 acc0 = {0.f,0.f,0.f,0.f}, acc1 = {0.f,0.f,0.f,0.f};
        #pragma unroll
        for (int kk = 0; kk < 8; ++kk) {
            // swizzled read: row jr=ct*16+l, granule (kk*4+q)^((l&7)<<2)  -> 2-way banks (free)
            const bf16x8 bfrag = *(const bf16x8*)&Ms[(ct * 16 + l) * HID_ +
                                                     (((kk * 4 + q) ^ ((l & 7) << 2)) << 3)];
            acc0 = __builtin_amdgcn_mfma_f32_16x16x32_bf16(afrag[0][kk], bfrag, acc0, 0, 0, 0);
            acc1 = __builtin_amdgcn_mfma_f32_16x16x32_bf16(afrag[1][kk], bfrag, acc1, 0, 0, 0);
        }
        // fused epilogue: part += (T - v2) * x   (C/D layout: col=lane&15, row=quad*4+reg)
        const float vv = v2l[ct];
        #pragma unroll
        for (int r = 0; r < 4; ++r) {
            part[r]     += (acc0[r] - vv) * xl[r];
            part[4 + r] += (acc1[r] - vv) * xl[4 + r];
        }
    }

    // reduce across the 16 col-lanes of each quad
    #pragma unroll
    for (int i = 0; i < 8; ++i) {
        float v = part[i];
        v += __shfl_xor(v, 1);
        v += __shfl_xor(v, 2);
        v += __shfl_xor(v, 4);
        v += __shfl_xor(v, 8);
        part[i] = v;
    }
    if (l == 0) {
        float* pb = p + (size_t)jh * (B_ * N_);
        #pragma unroll
        for (int i = 0; i < 8; ++i) {
            const int row = bh * 256 + wave * 32 + (i >> 2) * 16 + q * 4 + (i & 3);
            pb[(size_t)row * N_ + n] = part[i];
        }
    }
}

// ---------------- finalize (+fused loss): distmat = sqrt(p0 + p1 + c[n] + 1e-12),
// loss partial = sum of label-selected entries (exactly 2 per 256-thread block),
// atomicAdd'ed /B onto out[0] (pre-initialized with clip residue by prep).
__global__ __launch_bounds__(256) void finalize_kernel(
    const float* __restrict__ p, const float* __restrict__ cpart,
    const int* __restrict__ labels, float* __restrict__ out)
{
    __shared__ float sc[128];
    __shared__ float ls[4];
    const int t = threadIdx.x;
    if (t < 128) {
        float s = 0.f;
        #pragma unroll
        for (int g = 0; g < 8; ++g) s += cpart[t * 8 + g];
        sc[t] = s;
    }
    __syncthreads();
    const int i = blockIdx.x * 256 + t;             // 0..131071
    const int n = i & (N_ - 1);
    const int b = i >> 7;
    const float d = sqrtf(p[i] + p[B_ * N_ + i] + sc[n] + 1e-12f);
    out[1 + i] = d;
    float sel = (labels[b] == n) ? d : 0.f;
    #pragma unroll
    for (int m = 1; m <= 32; m <<= 1) sel += __shfl_xor(sel, m);
    if ((t & 63) == 0) ls[t >> 6] = sel;
    __syncthreads();
    if (t == 0) atomicAdd(out, (ls[0] + ls[1] + ls[2] + ls[3]) * (1.f / (float)B_));
}

extern "C" void kernel_launch(void* const* d_in, const int* in_sizes, int n_in,
                              void* d_out, int out_size, void* d_ws, size_t ws_size,
                              hipStream_t stream) {
    const float* x      = (const float*)d_in[0];
    const int*   labels = (const int*)d_in[1];
    const float* W      = (const float*)d_in[2];
    const float* bias   = (const float*)d_in[3];
    const float* means  = (const float*)d_in[4];
    const float* invcov = (const float*)d_in[5];
    float* out = (float*)d_out;

    // workspace carve-up (~19.5 MB total)
    char* ws = (char*)d_ws;
    unsigned short* Mbf   = (unsigned short*)(ws);               // 16,777,216 B
    float*          xp    = (float*)         (ws + 16777216);    //  1,048,576 B
    unsigned short* xbf   = (unsigned short*)(ws + 17825792);    //    524,288 B
    float*          v2    = (float*)         (ws + 18350080);    //    131,072 B
    float*          cpart = (float*)         (ws + 18481152);    //      4,096 B
    float*          p     = (float*)         (ws + 18489344);    //  1,048,576 B

    constexpr int DIST_LDS = 128 * HID_ * 2;   // 65536 B dynamic LDS
    (void)hipFuncSetAttribute((const void*)dist_kernel,
                              hipFuncAttributeMaxDynamicSharedMemorySize, DIST_LDS);

    prep_kernel<<<dim3(1536), 512, 0, stream>>>(x, W, bias, means, invcov,
                                                xp, xbf, Mbf, v2, cpart, out);
    dist_kernel<<<dim3(4, 2, N_), 512, DIST_LDS, stream>>>(xp, xbf, Mbf, v2, p);
    finalize_kernel<<<dim3((B_ * N_) / 256), 256, 0, stream>>>(p, cpart, labels, out);
}